// Round 1
// 4388.412 us; speedup vs baseline: 1.3510x; 1.3510x over previous
//
#include <hip/hip_runtime.h>

#define D_MODEL 1024
#define NH 16
#define DH 64
#define NL 12
#define TSEQ 1024
#define BT 4096  // B*T

typedef __attribute__((ext_vector_type(8))) short short8;
typedef __attribute__((ext_vector_type(4))) short short4v;
typedef __attribute__((ext_vector_type(4))) float floatx4;
typedef __attribute__((ext_vector_type(8))) __bf16 bf16x8;

__device__ __forceinline__ bf16x8 as_bf(short8 s) { return __builtin_bit_cast(bf16x8, s); }

// fp32 -> bf16 (RNE), returned as raw 16-bit pattern
__device__ __forceinline__ short f2bf(float f) {
  unsigned u = __builtin_bit_cast(unsigned, f);
  u += 0x7fffu + ((u >> 16) & 1u);
  return (short)(u >> 16);
}

// async global -> LDS, 16B per lane. LDS dest is wave-uniform base + lane*16.
__device__ __forceinline__ void gload16(const void* g, void* l) {
  __builtin_amdgcn_global_load_lds(
      (const __attribute__((address_space(1))) void*)g,
      (__attribute__((address_space(3))) void*)l, 16, 0, 0);
}

// ---------------- LayerNorm (+mask) fp32 -> bf16 ----------------
__global__ __launch_bounds__(256) void ln_kernel(const float* __restrict__ x,
                                                 const float* __restrict__ mvec,
                                                 const float* __restrict__ g,
                                                 const float* __restrict__ b,
                                                 short* __restrict__ h) {
  int row = blockIdx.x;
  const float* xr = x + (size_t)row * D_MODEL;
  int c = threadIdx.x * 4;
  float4 v = *(const float4*)(xr + c);
  float s = v.x + v.y + v.z + v.w;
  float s2 = v.x * v.x + v.y * v.y + v.z * v.z + v.w * v.w;
#pragma unroll
  for (int off = 1; off < 64; off <<= 1) {
    s += __shfl_xor(s, off);
    s2 += __shfl_xor(s2, off);
  }
  __shared__ float red[8];
  int wave = threadIdx.x >> 6, lane = threadIdx.x & 63;
  if (lane == 0) { red[wave] = s; red[4 + wave] = s2; }
  __syncthreads();
  s = red[0] + red[1] + red[2] + red[3];
  s2 = red[4] + red[5] + red[6] + red[7];
  float mu = s * (1.0f / D_MODEL);
  float var = s2 * (1.0f / D_MODEL) - mu * mu;
  float rstd = rsqrtf(var + 1e-5f);
  float mm = mvec[row];
  float4 gv = *(const float4*)(g + c);
  float4 bv = *(const float4*)(b + c);
  short4v o;
  o[0] = f2bf(((v.x - mu) * rstd * gv.x + bv.x) * mm);
  o[1] = f2bf(((v.y - mu) * rstd * gv.y + bv.y) * mm);
  o[2] = f2bf(((v.z - mu) * rstd * gv.z + bv.z) * mm);
  o[3] = f2bf(((v.w - mu) * rstd * gv.w + bv.w) * mm);
  *(short4v*)(h + (size_t)row * D_MODEL + c) = o;
}

// ---------------- Weight prep: W f32 [K][N] -> Wt bf16 [N][K] ----------------
// One launch per layer covers all 4 weight matrices via blockIdx segments.
// 32x32 tile transpose through LDS. Purely BW-bound (~12 us/layer).
__global__ __launch_bounds__(256) void prep_kernel(
    const float* __restrict__ wqkv, const float* __restrict__ wout,
    const float* __restrict__ w1, const float* __restrict__ w2,
    short* __restrict__ wqkvt, short* __restrict__ woutt,
    short* __restrict__ w1t, short* __restrict__ w2t) {
  int bid = blockIdx.x;
  const float* W;
  short* Wt;
  int K, N, tile;
  if (bid < 3072) {            // wqkv: K=1024, N=3072 -> 96*32 tiles
    W = wqkv; Wt = wqkvt; K = 1024; N = 3072; tile = bid;
  } else if (bid < 4096) {     // wout: 1024x1024 -> 32*32 tiles
    W = wout; Wt = woutt; K = 1024; N = 1024; tile = bid - 3072;
  } else if (bid < 8192) {     // w1: K=1024, N=4096 -> 128*32 tiles
    W = w1; Wt = w1t; K = 1024; N = 4096; tile = bid - 4096;
  } else {                     // w2: K=4096, N=1024 -> 32*128 tiles
    W = w2; Wt = w2t; K = 4096; N = 1024; tile = bid - 8192;
  }
  int ntn = N >> 5;
  int tn = tile % ntn, tk = tile / ntn;
  __shared__ float lds[32 * 33];
  int t = threadIdx.x;
  int r = t >> 3, cg = (t & 7) * 4;
  float4 v = *(const float4*)(W + (size_t)(tk * 32 + r) * N + tn * 32 + cg);
  lds[r * 33 + cg + 0] = v.x;
  lds[r * 33 + cg + 1] = v.y;
  lds[r * 33 + cg + 2] = v.z;
  lds[r * 33 + cg + 3] = v.w;
  __syncthreads();
  short4v o;
#pragma unroll
  for (int j = 0; j < 4; j++) o[j] = f2bf(lds[(cg + j) * 33 + r]);
  *(short4v*)(Wt + (size_t)(tn * 32 + r) * K + tk * 32 + cg) = o;
}

// ---------------- GEMM: C = A(bf16, MxK) @ Wt(bf16, NxK)^T ----------------
// m97 structure: 128x128 tile, BK=32, global_load_lds(16B) staging, linear LDS,
// 2-barrier K-loop, 16 MFMA + 8 ds_read_b128 per K-step.
// EPI 0: plain -> bf16 out
// EPI 1: out_f = (res + (acc + bias)*m) * m     (attention residual)
// EPI 2: gelu_exact(acc + bias) -> bf16 out     (FFN up)
// EPI 3: out_f = (res + acc + bias) * m         (FFN residual)
template <int EPI>
__global__ __launch_bounds__(256) void gemm_kernel(
    const short* __restrict__ A, const short* __restrict__ Wt,
    const float* __restrict__ bias, const float* __restrict__ res,
    const float* __restrict__ mvec, short* __restrict__ out_bf,
    float* __restrict__ out_f, int M, int N, int K) {
  __shared__ __align__(16) short As[128 * 32];  // [row][k], linear (gload_lds dest)
  __shared__ __align__(16) short Bs[128 * 32];  // [n][k],   linear

  int t = threadIdx.x;
  int lane = t & 63, w = t >> 6;
  int wm = w >> 1, wn = w & 1;
  int q4 = lane >> 4, r16 = lane & 15;
  int m0 = blockIdx.y * 128, n0 = blockIdx.x * 128;
  floatx4 acc[4][4] = {};

  // staging: chunk c = 16 rows = 1024B; wave w owns chunks {2w, 2w+1} of A and B.
  // lane l covers row c*16 + (l>>2), k-offset (l&3)*8 (16B).
  int srow = lane >> 2;
  int skof = (lane & 3) * 8;
  const short* gA0 = A + (size_t)(m0 + (w * 2 + 0) * 16 + srow) * K + skof;
  const short* gA1 = A + (size_t)(m0 + (w * 2 + 1) * 16 + srow) * K + skof;
  const short* gB0 = Wt + (size_t)(n0 + (w * 2 + 0) * 16 + srow) * K + skof;
  const short* gB1 = Wt + (size_t)(n0 + (w * 2 + 1) * 16 + srow) * K + skof;
  short* lA0 = As + (w * 2 + 0) * 512;  // 512 shorts = 1024B chunk
  short* lA1 = As + (w * 2 + 1) * 512;
  short* lB0 = Bs + (w * 2 + 0) * 512;
  short* lB1 = Bs + (w * 2 + 1) * 512;

  for (int k0 = 0; k0 < K; k0 += 32) {
    __syncthreads();  // previous iteration's LDS reads complete
    gload16(gA0 + k0, lA0);
    gload16(gA1 + k0, lA1);
    gload16(gB0 + k0, lB0);
    gload16(gB1 + k0, lB1);
    __syncthreads();  // compiler emits s_waitcnt vmcnt(0) before s_barrier
    bf16x8 af[4], bfv[4];
#pragma unroll
    for (int mt = 0; mt < 4; mt++)
      af[mt] = as_bf(*(const short8*)(As + (wm * 64 + mt * 16 + r16) * 32 + q4 * 8));
#pragma unroll
    for (int nt = 0; nt < 4; nt++)
      bfv[nt] = as_bf(*(const short8*)(Bs + (wn * 64 + nt * 16 + r16) * 32 + q4 * 8));
#pragma unroll
    for (int mt = 0; mt < 4; mt++)
#pragma unroll
      for (int nt = 0; nt < 4; nt++)
        acc[mt][nt] = __builtin_amdgcn_mfma_f32_16x16x32_bf16(af[mt], bfv[nt], acc[mt][nt], 0, 0, 0);
  }

#pragma unroll
  for (int mt = 0; mt < 4; mt++) {
#pragma unroll
    for (int nt = 0; nt < 4; nt++) {
      int col = n0 + wn * 64 + nt * 16 + r16;
#pragma unroll
      for (int rr = 0; rr < 4; rr++) {
        int row = m0 + wm * 64 + mt * 16 + q4 * 4 + rr;
        float v = acc[mt][nt][rr];
        if (EPI == 0) {
          out_bf[(size_t)row * N + col] = f2bf(v);
        } else if (EPI == 1) {
          float mm = mvec[row];
          out_f[(size_t)row * N + col] =
              (res[(size_t)row * N + col] + (v + bias[col]) * mm) * mm;
        } else if (EPI == 2) {
          v += bias[col];
          v = 0.5f * v * (1.0f + erff(v * 0.70710678118654752f));
          out_bf[(size_t)row * N + col] = f2bf(v);
        } else {
          float mm = mvec[row];
          out_f[(size_t)row * N + col] =
              (res[(size_t)row * N + col] + v + bias[col]) * mm;
        }
      }
    }
  }
}

// ---------------- Flash attention (causal), 64 Q rows / block ----------------
__global__ __launch_bounds__(256) void attn_kernel(const short* __restrict__ qkv,
                                                   short* __restrict__ o) {
  __shared__ __align__(16) short Vs[64 * 72];  // [dh][j] stride 72, j 8-group XOR swizzled
  __shared__ __align__(16) short Ps[64 * 72];  // [i (4 waves x 16)][j] stride 72

  int t = threadIdx.x, lane = t & 63, w = t >> 6;
  int q4 = lane >> 4, r16 = lane & 15;
  int qt = blockIdx.x & 15, bh = blockIdx.x >> 4;
  int b = bh >> 4, h = bh & 15;
  int q0 = qt * 64;
  const short* base = qkv + (size_t)b * TSEQ * 3072;

  bf16x8 qf[2];
  {
    int qrow = q0 + w * 16 + r16;
#pragma unroll
    for (int kc = 0; kc < 2; kc++)
      qf[kc] = as_bf(*(const short8*)(base + (size_t)qrow * 3072 + h * 64 + kc * 32 + q4 * 8));
  }
  floatx4 oacc[4] = {};
  float mi[4], li[4];
#pragma unroll
  for (int rr = 0; rr < 4; rr++) { mi[rr] = -1e30f; li[rr] = 0.0f; }
  int vj = t >> 2, vd0 = (t & 3) * 16;

  for (int j0 = 0; j0 <= q0; j0 += 64) {
    // V tile global loads (to regs; LDS write after barrier)
    const short* vg = base + (size_t)(j0 + vj) * 3072 + 2048 + h * 64 + vd0;
    short8 vv0 = *(const short8*)vg;
    short8 vv1 = *(const short8*)(vg + 8);
    // S = Q @ K^T (K frags straight from global: B[k=d][n=j] = K[j][d])
    floatx4 sacc[4] = {};
#pragma unroll
    for (int nt = 0; nt < 4; nt++) {
#pragma unroll
      for (int kc = 0; kc < 2; kc++) {
        bf16x8 kf = as_bf(*(const short8*)(base + (size_t)(j0 + nt * 16 + r16) * 3072 +
                                           1024 + h * 64 + kc * 32 + q4 * 8));
        sacc[nt] = __builtin_amdgcn_mfma_f32_16x16x32_bf16(qf[kc], kf, sacc[nt], 0, 0, 0);
      }
    }
    float sm[4][4];
#pragma unroll
    for (int nt = 0; nt < 4; nt++)
#pragma unroll
      for (int rr = 0; rr < 4; rr++) {
        float sv = sacc[nt][rr] * 0.125f;
        if (j0 == q0) {
          int jg = j0 + nt * 16 + r16;
          int ig = q0 + w * 16 + q4 * 4 + rr;
          if (jg > ig) sv = -3.0e38f;
        }
        sm[nt][rr] = sv;
      }
    float alpha[4];
#pragma unroll
    for (int rr = 0; rr < 4; rr++) {
      float v = fmaxf(fmaxf(sm[0][rr], sm[1][rr]), fmaxf(sm[2][rr], sm[3][rr]));
      v = fmaxf(v, __shfl_xor(v, 1));
      v = fmaxf(v, __shfl_xor(v, 2));
      v = fmaxf(v, __shfl_xor(v, 4));
      v = fmaxf(v, __shfl_xor(v, 8));
      float mnew = fmaxf(mi[rr], v);
      float al = __expf(mi[rr] - mnew);
      float ls = 0.0f;
#pragma unroll
      for (int nt = 0; nt < 4; nt++) {
        float p = __expf(sm[nt][rr] - mnew);
        sm[nt][rr] = p;
        ls += p;
      }
      ls += __shfl_xor(ls, 1);
      ls += __shfl_xor(ls, 2);
      ls += __shfl_xor(ls, 4);
      ls += __shfl_xor(ls, 8);
      li[rr] = li[rr] * al + ls;
      mi[rr] = mnew;
      alpha[rr] = al;
    }
#pragma unroll
    for (int nt = 0; nt < 4; nt++)
#pragma unroll
      for (int rr = 0; rr < 4; rr++) oacc[nt][rr] *= alpha[rr];

    __syncthreads();  // previous iteration's Vs/Ps reads complete
#pragma unroll
    for (int i = 0; i < 16; i++) {
      int dh = vd0 + i;
      int jsw = (vj & 7) | ((((vj >> 3) ^ (dh >> 4)) & 7) << 3);
      Vs[dh * 72 + jsw] = (i < 8) ? vv0[i] : vv1[i - 8];
    }
#pragma unroll
    for (int nt = 0; nt < 4; nt++)
#pragma unroll
      for (int rr = 0; rr < 4; rr++)
        Ps[(w * 16 + q4 * 4 + rr) * 72 + nt * 16 + r16] = f2bf(sm[nt][rr]);
    __syncthreads();

    bf16x8 pf[2];
#pragma unroll
    for (int kc = 0; kc < 2; kc++)
      pf[kc] = as_bf(*(const short8*)(Ps + (w * 16 + r16) * 72 + kc * 32 + q4 * 8));
#pragma unroll
    for (int nt = 0; nt < 4; nt++) {
#pragma unroll
      for (int kc = 0; kc < 2; kc++) {
        bf16x8 vf = as_bf(*(const short8*)(Vs + (nt * 16 + r16) * 72 +
                                           ((((kc * 4 + q4) ^ nt) & 7) << 3)));
        oacc[nt] = __builtin_amdgcn_mfma_f32_16x16x32_bf16(pf[kc], vf, oacc[nt], 0, 0, 0);
      }
    }
  }
#pragma unroll
  for (int rr = 0; rr < 4; rr++) {
    float inv = 1.0f / li[rr];
    int row = b * TSEQ + q0 + w * 16 + q4 * 4 + rr;
#pragma unroll
    for (int nt = 0; nt < 4; nt++)
      o[(size_t)row * D_MODEL + h * 64 + nt * 16 + r16] = f2bf(oacc[nt][rr] * inv);
  }
}

extern "C" void kernel_launch(void* const* d_in, const int* in_sizes, int n_in,
                              void* d_out, int out_size, void* d_ws, size_t ws_size,
                              hipStream_t stream) {
  const float* x    = (const float*)d_in[0];
  const float* m    = (const float*)d_in[1];
  const float* ln1g = (const float*)d_in[2];
  const float* ln1b = (const float*)d_in[3];
  const float* wqkv = (const float*)d_in[4];
  const float* wout = (const float*)d_in[5];
  const float* bout = (const float*)d_in[6];
  const float* ln2g = (const float*)d_in[7];
  const float* ln2b = (const float*)d_in[8];
  const float* w1   = (const float*)d_in[9];
  const float* b1   = (const float*)d_in[10];
  const float* w2   = (const float*)d_in[11];
  const float* b2   = (const float*)d_in[12];

  float* xbuf = (float*)d_out;  // running residual stream lives in d_out
  char* ws = (char*)d_ws;
  short* h     = (short*)(ws);                 //  8 MB (4096x1024 bf16)
  short* qkv   = (short*)(ws + (8u << 20));    // 24 MB (4096x3072 bf16)
  short* obuf  = (short*)(ws + (32u << 20));   //  8 MB (4096x1024 bf16)
  short* ff1   = (short*)(ws + (40u << 20));   // 32 MB (4096x4096 bf16)
  short* wqkvt = (short*)(ws + (72u << 20));   //  6 MB (3072x1024 bf16)
  short* woutt = (short*)(ws + (78u << 20));   //  2 MB (1024x1024 bf16)
  short* w1t   = (short*)(ws + (80u << 20));   //  8 MB (4096x1024 bf16)
  short* w2t   = (short*)(ws + (88u << 20));   //  8 MB (1024x4096 bf16) -> end 96 MB

  hipMemcpyAsync(xbuf, x, (size_t)BT * D_MODEL * sizeof(float),
                 hipMemcpyDeviceToDevice, stream);

  for (int l = 0; l < NL; l++) {
    prep_kernel<<<12288, 256, 0, stream>>>(
        wqkv + (size_t)l * D_MODEL * 3072, wout + (size_t)l * D_MODEL * D_MODEL,
        w1 + (size_t)l * D_MODEL * 4096, w2 + (size_t)l * 4096 * D_MODEL,
        wqkvt, woutt, w1t, w2t);
    ln_kernel<<<BT, 256, 0, stream>>>(xbuf, m, ln1g + l * D_MODEL, ln1b + l * D_MODEL, h);
    gemm_kernel<0><<<dim3(24, 32), 256, 0, stream>>>(
        h, wqkvt, nullptr, nullptr, nullptr, qkv, nullptr, BT, 3072, D_MODEL);
    attn_kernel<<<1024, 256, 0, stream>>>(qkv, obuf);
    gemm_kernel<1><<<dim3(8, 32), 256, 0, stream>>>(
        obuf, woutt, bout + l * D_MODEL, xbuf, m, nullptr, xbuf, BT, D_MODEL, D_MODEL);
    ln_kernel<<<BT, 256, 0, stream>>>(xbuf, m, ln2g + l * D_MODEL, ln2b + l * D_MODEL, h);
    gemm_kernel<2><<<dim3(32, 32), 256, 0, stream>>>(
        h, w1t, b1 + (size_t)l * 4096, nullptr, nullptr, ff1, nullptr, BT, 4096, D_MODEL);
    gemm_kernel<3><<<dim3(8, 32), 256, 0, stream>>>(
        ff1, w2t, b2 + l * D_MODEL, xbuf, m, nullptr, xbuf, BT, D_MODEL, 4096);
  }
}